// Round 1
// baseline (773.702 us; speedup 1.0000x reference)
//
#include <hip/hip_runtime.h>
#include <hip/hip_bf16.h>

#define N_NODES 50000
#define HEADS 8
#define CHANS 10
#define HC 80
#define F_IN 128
#define E_EDGES 1600000
#define E_TOT (E_EDGES + N_NODES)
#define NEG_SLOPE 0.2f

// ---------------------------------------------------------------------------
// Detect whether edge_index arrived as int64 (odd int32 words all zero) or int32
__global__ void detect_mode_kernel(const void* ei, int* flag) {
    const int* p = (const int*)ei;
    int is64 = 1;
    for (int k = 1; k < 256; k += 2) {
        if (p[k] != 0) { is64 = 0; break; }
    }
    *flag = is64;
}

// ---------------------------------------------------------------------------
__global__ void count_deg_kernel(const void* ei, const int* __restrict__ flag,
                                 int* __restrict__ deg) {
    int e = blockIdx.x * blockDim.x + threadIdx.x;
    if (e >= E_TOT) return;
    int dst;
    if (e < E_EDGES) {
        if (*flag) dst = (int)((const long long*)ei)[E_EDGES + e];
        else       dst = ((const int*)ei)[E_EDGES + e];
    } else {
        dst = e - E_EDGES;
    }
    atomicAdd(&deg[dst], 1);
}

// ---------------------------------------------------------------------------
// Single-block hierarchical exclusive scan over deg[N_NODES] -> row_ptr, cursor
__global__ void scan_kernel(const int* __restrict__ deg, int* __restrict__ row_ptr,
                            int* __restrict__ cursor) {
    __shared__ int wsum[16];
    __shared__ int wpre[16];
    __shared__ int carry;
    int tid = threadIdx.x;
    int lane = tid & 63, w = tid >> 6;
    if (tid == 0) carry = 0;
    __syncthreads();
    for (int base = 0; base < N_NODES; base += 1024) {
        int idx = base + tid;
        int v = (idx < N_NODES) ? deg[idx] : 0;
        int sv = v;
        #pragma unroll
        for (int off = 1; off < 64; off <<= 1) {
            int t = __shfl_up(sv, off, 64);
            if (lane >= off) sv += t;
        }
        if (lane == 63) wsum[w] = sv;
        __syncthreads();
        if (w == 0) {
            int s = (lane < 16) ? wsum[lane] : 0;
            #pragma unroll
            for (int off = 1; off < 16; off <<= 1) {
                int t = __shfl_up(s, off, 64);
                if (lane >= off) s += t;
            }
            if (lane < 16) wpre[lane] = s;
        }
        __syncthreads();
        int pre = carry + ((w > 0) ? wpre[w - 1] : 0);
        int excl = pre + sv - v;
        if (idx < N_NODES) { row_ptr[idx] = excl; cursor[idx] = excl; }
        __syncthreads();
        if (tid == 0) carry += wpre[15];
        __syncthreads();
    }
    if (tid == 0) row_ptr[N_NODES] = carry;
}

// ---------------------------------------------------------------------------
__global__ void scatter_kernel(const void* ei, const int* __restrict__ flag,
                               int* __restrict__ cursor, int* __restrict__ csr_src) {
    int e = blockIdx.x * blockDim.x + threadIdx.x;
    if (e >= E_TOT) return;
    int src, dst;
    if (e < E_EDGES) {
        if (*flag) {
            src = (int)((const long long*)ei)[e];
            dst = (int)((const long long*)ei)[E_EDGES + e];
        } else {
            src = ((const int*)ei)[e];
            dst = ((const int*)ei)[E_EDGES + e];
        }
    } else {
        src = dst = e - E_EDGES;
    }
    int pos = atomicAdd(&cursor[dst], 1);
    csr_src[pos] = src;
}

// ---------------------------------------------------------------------------
// xl = x @ Wl, xr = x @ Wr.  x: [N, din], Wl/Wr: [din, 80].
// Block: 256 threads, tile = 64 nodes x 160 cols, K-tile = 16.
__global__ __launch_bounds__(256) void gemm_xlxr_kernel(
        const float* __restrict__ x, const float* __restrict__ wl,
        const float* __restrict__ wr, int din,
        float* __restrict__ xl, float* __restrict__ xr) {
    __shared__ float xs[16 * 64];    // [k][node]
    __shared__ float ws[16 * 160];   // [k][col]
    int tid = threadIdx.x;
    int n0 = blockIdx.x * 64;
    int tn = tid >> 4, tc = tid & 15;
    float acc[4][10];
    #pragma unroll
    for (int i = 0; i < 4; i++)
        #pragma unroll
        for (int j = 0; j < 10; j++) acc[i][j] = 0.f;

    int nkt = din >> 4;
    int lr = tid >> 2;          // node 0..63
    int lc = (tid & 3) * 4;     // k offset 0,4,8,12

    for (int kt = 0; kt < nkt; kt++) {
        float4 xv4 = make_float4(0.f, 0.f, 0.f, 0.f);
        int n = n0 + lr;
        if (n < N_NODES)
            xv4 = *(const float4*)(x + (size_t)n * din + kt * 16 + lc);
        __syncthreads();   // protect previous iteration's LDS reads
        xs[(lc + 0) * 64 + lr] = xv4.x;
        xs[(lc + 1) * 64 + lr] = xv4.y;
        xs[(lc + 2) * 64 + lr] = xv4.z;
        xs[(lc + 3) * 64 + lr] = xv4.w;
        #pragma unroll
        for (int rep = 0; rep < 10; rep++) {
            int flat = rep * 256 + tid;
            int k = flat / 160, c = flat % 160;
            int kg = kt * 16 + k;
            float wv = (c < 80) ? wl[kg * 80 + c] : wr[kg * 80 + (c - 80)];
            ws[k * 160 + c] = wv;
        }
        __syncthreads();
        #pragma unroll
        for (int k = 0; k < 16; k++) {
            float4 xv = *(const float4*)(&xs[k * 64 + tn * 4]);
            float xa[4] = {xv.x, xv.y, xv.z, xv.w};
            #pragma unroll
            for (int j = 0; j < 10; j++) {
                float wv = ws[k * 160 + tc * 10 + j];
                #pragma unroll
                for (int i = 0; i < 4; i++) acc[i][j] += xa[i] * wv;
            }
        }
    }
    float* outp = (tc < 8) ? xl : xr;
    int cbase = (tc < 8) ? tc * 10 : (tc - 8) * 10;
    #pragma unroll
    for (int i = 0; i < 4; i++) {
        int n = n0 + tn * 4 + i;
        if (n < N_NODES) {
            #pragma unroll
            for (int j = 0; j < 10; j++)
                outp[(size_t)n * HC + cbase + j] = acc[i][j];
        }
    }
}

// ---------------------------------------------------------------------------
// One thread per (node, head): online-softmax aggregation over incoming edges.
// Lane groups of 8 = the 8 heads of one node -> coalesced 320B xl-row gathers.
__global__ __launch_bounds__(256) void aggregate_kernel(
        const float* __restrict__ xl, const float* __restrict__ xr,
        const float* __restrict__ att, const float* __restrict__ bias,
        const int* __restrict__ row_ptr, const int* __restrict__ csr_src,
        float* __restrict__ y) {
    int g = blockIdx.x * blockDim.x + threadIdx.x;
    if (g >= N_NODES * HEADS) return;
    int i = g >> 3, h = g & 7;

    float xr_c[CHANS], att_c[CHANS];
    #pragma unroll
    for (int c = 0; c < CHANS; c++) {
        xr_c[c]  = xr[(size_t)i * HC + h * CHANS + c];
        att_c[c] = att[h * CHANS + c];
    }
    float m = -INFINITY, l = 0.f;
    float acc[CHANS];
    #pragma unroll
    for (int c = 0; c < CHANS; c++) acc[c] = 0.f;

    int s0 = row_ptr[i], s1 = row_ptr[i + 1];
    for (int k = s0; k < s1; k++) {
        int j = csr_src[k];
        const float* xlp = xl + (size_t)j * HC + h * CHANS;
        float v[CHANS];
        float s = 0.f;
        #pragma unroll
        for (int c = 0; c < CHANS; c++) {
            v[c] = xlp[c];
            float t = v[c] + xr_c[c];
            t = (t > 0.f) ? t : NEG_SLOPE * t;
            s += att_c[c] * t;
        }
        float mn = fmaxf(m, s);
        float scale = __expf(m - mn);   // exp(-inf) = 0 on first edge
        float p = __expf(s - mn);
        l = l * scale + p;
        #pragma unroll
        for (int c = 0; c < CHANS; c++) acc[c] = acc[c] * scale + p * v[c];
        m = mn;
    }
    float inv = 1.f / (l + 1e-16f);
    #pragma unroll
    for (int c = 0; c < CHANS; c++) {
        float z = acc[c] * inv + bias[h * CHANS + c];
        y[(size_t)i * HC + h * CHANS + c] = (z > 0.f) ? z : (__expf(z) - 1.f);
    }
}

// ---------------------------------------------------------------------------
extern "C" void kernel_launch(void* const* d_in, const int* in_sizes, int n_in,
                              void* d_out, int out_size, void* d_ws, size_t ws_size,
                              hipStream_t stream) {
    const float* x_in = (const float*)d_in[0];
    const void*  ei   = d_in[1];
    const float* Wl[3] = {(const float*)d_in[2], (const float*)d_in[6],  (const float*)d_in[10]};
    const float* Wr[3] = {(const float*)d_in[3], (const float*)d_in[7],  (const float*)d_in[11]};
    const float* At[3] = {(const float*)d_in[4], (const float*)d_in[8],  (const float*)d_in[12]};
    const float* Bi[3] = {(const float*)d_in[5], (const float*)d_in[9],  (const float*)d_in[13]};
    float* out = (float*)d_out;

    // workspace layout (256B aligned chunks)
    char* ws = (char*)d_ws;
    size_t off = 0;
    auto alloc = [&](size_t bytes) {
        void* p = ws + off;
        off += (bytes + 255) & ~(size_t)255;
        return p;
    };
    float* xl      = (float*)alloc((size_t)N_NODES * HC * sizeof(float));
    float* xr      = (float*)alloc((size_t)N_NODES * HC * sizeof(float));
    float* buf     = (float*)alloc((size_t)N_NODES * HC * sizeof(float));
    int*   csr_src = (int*)alloc((size_t)E_TOT * sizeof(int));
    int*   row_ptr = (int*)alloc((size_t)(N_NODES + 1) * sizeof(int));
    int*   cursor  = (int*)alloc((size_t)N_NODES * sizeof(int));
    int*   deg     = (int*)alloc((size_t)N_NODES * sizeof(int));
    int*   flag    = (int*)alloc(256);

    // --- build CSR by destination (once per launch) ---
    detect_mode_kernel<<<1, 1, 0, stream>>>(ei, flag);
    hipMemsetAsync(deg, 0, (size_t)N_NODES * sizeof(int), stream);
    int eblocks = (E_TOT + 255) / 256;
    count_deg_kernel<<<eblocks, 256, 0, stream>>>(ei, flag, deg);
    scan_kernel<<<1, 1024, 0, stream>>>(deg, row_ptr, cursor);
    scatter_kernel<<<eblocks, 256, 0, stream>>>(ei, flag, cursor, csr_src);

    // --- 3 GATv2 layers ---
    int gemm_blocks = (N_NODES + 63) / 64;
    int agg_blocks  = (N_NODES * HEADS + 255) / 256;

    const float* cur = x_in;
    int din = F_IN;
    for (int layer = 0; layer < 3; layer++) {
        gemm_xlxr_kernel<<<gemm_blocks, 256, 0, stream>>>(cur, Wl[layer], Wr[layer],
                                                          din, xl, xr);
        float* y = (layer == 2) ? out : buf;
        aggregate_kernel<<<agg_blocks, 256, 0, stream>>>(xl, xr, At[layer], Bi[layer],
                                                         row_ptr, csr_src, y);
        cur = buf;
        din = HC;
    }
}

// Round 2
// 745.649 us; speedup vs baseline: 1.0376x; 1.0376x over previous
//
#include <hip/hip_runtime.h>
#include <hip/hip_bf16.h>

#define N_NODES 50000
#define HEADS 8
#define CHANS 10
#define HC 80
#define F_IN 128
#define E_EDGES 1600000
#define E_TOT (E_EDGES + N_NODES)
#define NEG_SLOPE 0.2f
#define NBUCK 1563            // ceil(50000 / 32)
#define CAP 2048              // max edges per bucket fast path (mean 1088, sigma ~33)

// ---------------------------------------------------------------------------
// Detect whether edge_index arrived as int64 (odd int32 words all zero) or int32
__global__ void detect_mode_kernel(const void* ei, int* flag) {
    const int* p = (const int*)ei;
    int tid = threadIdx.x;
    bool ok = (p[2 * tid + 1] == 0) && (p[2 * (tid + 64) + 1] == 0);
    unsigned long long m = __ballot(ok);
    if (tid == 0) *flag = (m == ~0ull) ? 1 : 0;
}

// ---------------------------------------------------------------------------
// Per-bucket edge counts via per-block LDS histogram (32 dst nodes / bucket)
__global__ __launch_bounds__(256) void count_bucket_kernel(
        const void* ei, const int* __restrict__ flag, int* __restrict__ bcount) {
    __shared__ int h[NBUCK];
    for (int i = threadIdx.x; i < NBUCK; i += 256) h[i] = 0;
    __syncthreads();
    int is64 = *flag;
    for (int e = blockIdx.x * 256 + threadIdx.x; e < E_TOT; e += 256 * 256) {
        int dst;
        if (e < E_EDGES) {
            if (is64) dst = (int)((const long long*)ei)[E_EDGES + e];
            else      dst = ((const int*)ei)[E_EDGES + e];
        } else {
            dst = e - E_EDGES;
        }
        atomicAdd(&h[dst >> 5], 1);
    }
    __syncthreads();
    for (int i = threadIdx.x; i < NBUCK; i += 256)
        if (h[i]) atomicAdd(&bcount[i], h[i]);
}

// ---------------------------------------------------------------------------
// Single-block exclusive scan over bcount[NBUCK] -> bbase (+total), bcursor
__global__ void scan_buckets_kernel(const int* __restrict__ bcount,
                                    int* __restrict__ bbase, int* __restrict__ bcursor) {
    __shared__ int wsum[16];
    __shared__ int wpre[16];
    __shared__ int carry;
    int tid = threadIdx.x;
    int lane = tid & 63, w = tid >> 6;
    if (tid == 0) carry = 0;
    __syncthreads();
    for (int base = 0; base < NBUCK; base += 1024) {
        int idx = base + tid;
        int v = (idx < NBUCK) ? bcount[idx] : 0;
        int sv = v;
        #pragma unroll
        for (int off = 1; off < 64; off <<= 1) {
            int t = __shfl_up(sv, off, 64);
            if (lane >= off) sv += t;
        }
        if (lane == 63) wsum[w] = sv;
        __syncthreads();
        if (w == 0) {
            int s = (lane < 16) ? wsum[lane] : 0;
            #pragma unroll
            for (int off = 1; off < 16; off <<= 1) {
                int t = __shfl_up(s, off, 64);
                if (lane >= off) s += t;
            }
            if (lane < 16) wpre[lane] = s;
        }
        __syncthreads();
        int pre = carry + ((w > 0) ? wpre[w - 1] : 0);
        int excl = pre + sv - v;
        if (idx < NBUCK) { bbase[idx] = excl; bcursor[idx] = excl; }
        __syncthreads();
        if (tid == 0) carry += wpre[15];
        __syncthreads();
    }
    if (tid == 0) bbase[NBUCK] = carry;
}

// ---------------------------------------------------------------------------
// Phase-A scatter: append packed (src<<5 | dst&31) into the dst's bucket region.
// Write frontier = NBUCK hot cache lines (~100 KB) -> full lines flushed to HBM.
__global__ __launch_bounds__(256) void scatter_bucket_kernel(
        const void* ei, const int* __restrict__ flag,
        int* __restrict__ bcursor, int* __restrict__ tmp) {
    int e = blockIdx.x * 256 + threadIdx.x;
    if (e >= E_TOT) return;
    int src, dst;
    if (e < E_EDGES) {
        if (*flag) {
            src = (int)((const long long*)ei)[e];
            dst = (int)((const long long*)ei)[E_EDGES + e];
        } else {
            src = ((const int*)ei)[e];
            dst = ((const int*)ei)[E_EDGES + e];
        }
    } else {
        src = dst = e - E_EDGES;
    }
    int pos = atomicAdd(&bcursor[dst >> 5], 1);
    tmp[pos] = (src << 5) | (dst & 31);
}

// ---------------------------------------------------------------------------
// xl = x @ Wl, xr = x @ Wr.  x: [N, din], Wl/Wr: [din, 80].
__global__ __launch_bounds__(256) void gemm_xlxr_kernel(
        const float* __restrict__ x, const float* __restrict__ wl,
        const float* __restrict__ wr, int din,
        float* __restrict__ xl, float* __restrict__ xr) {
    __shared__ float xs[16 * 64];    // [k][node]
    __shared__ float ws[16 * 160];   // [k][col]
    int tid = threadIdx.x;
    int n0 = blockIdx.x * 64;
    int tn = tid >> 4, tc = tid & 15;
    float acc[4][10];
    #pragma unroll
    for (int i = 0; i < 4; i++)
        #pragma unroll
        for (int j = 0; j < 10; j++) acc[i][j] = 0.f;

    int nkt = din >> 4;
    int lr = tid >> 2;
    int lc = (tid & 3) * 4;

    for (int kt = 0; kt < nkt; kt++) {
        float4 xv4 = make_float4(0.f, 0.f, 0.f, 0.f);
        int n = n0 + lr;
        if (n < N_NODES)
            xv4 = *(const float4*)(x + (size_t)n * din + kt * 16 + lc);
        __syncthreads();
        xs[(lc + 0) * 64 + lr] = xv4.x;
        xs[(lc + 1) * 64 + lr] = xv4.y;
        xs[(lc + 2) * 64 + lr] = xv4.z;
        xs[(lc + 3) * 64 + lr] = xv4.w;
        #pragma unroll
        for (int rep = 0; rep < 10; rep++) {
            int flat = rep * 256 + tid;
            int k = flat / 160, c = flat % 160;
            int kg = kt * 16 + k;
            float wv = (c < 80) ? wl[kg * 80 + c] : wr[kg * 80 + (c - 80)];
            ws[k * 160 + c] = wv;
        }
        __syncthreads();
        #pragma unroll
        for (int k = 0; k < 16; k++) {
            float4 xv = *(const float4*)(&xs[k * 64 + tn * 4]);
            float xa[4] = {xv.x, xv.y, xv.z, xv.w};
            #pragma unroll
            for (int j = 0; j < 10; j++) {
                float wv = ws[k * 160 + tc * 10 + j];
                #pragma unroll
                for (int i = 0; i < 4; i++) acc[i][j] += xa[i] * wv;
            }
        }
    }
    float* outp = (tc < 8) ? xl : xr;
    int cbase = (tc < 8) ? tc * 10 : (tc - 8) * 10;
    #pragma unroll
    for (int i = 0; i < 4; i++) {
        int n = n0 + tn * 4 + i;
        if (n < N_NODES) {
            #pragma unroll
            for (int j = 0; j < 10; j++)
                outp[(size_t)n * HC + cbase + j] = acc[i][j];
        }
    }
}

// ---------------------------------------------------------------------------
// Fused per-bucket sort + online-softmax aggregation.
// Block = bucket = 32 nodes x 8 heads = 256 threads.
__global__ __launch_bounds__(256) void fused_agg_kernel(
        const float* __restrict__ xl, const float* __restrict__ xr,
        const float* __restrict__ att, const float* __restrict__ bias,
        const int* __restrict__ bbase, const int* __restrict__ tmp,
        float* __restrict__ y) {
    __shared__ int stage[CAP];
    __shared__ int hist[32];
    __shared__ int startc[32];
    __shared__ int cursors[32];
    int tid = threadIdx.x;
    int b = blockIdx.x;
    int base = bbase[b];
    int n = bbase[b + 1] - base;

    int i_local = tid >> 3, h = tid & 7;
    int node = b * 32 + i_local;

    bool fast = (n <= CAP);
    int myst = 0, mycnt = 0;
    if (fast) {
        if (tid < 32) hist[tid] = 0;
        __syncthreads();
        int pk[CAP / 256];
        int nk = (n + 255) >> 8;
        for (int kk = 0; kk < nk; kk++) {
            int idx = kk * 256 + tid;
            pk[kk] = -1;
            if (idx < n) {
                int p = tmp[base + idx];
                pk[kk] = p;
                atomicAdd(&hist[p & 31], 1);
            }
        }
        __syncthreads();
        if (tid == 0) {
            int run = 0;
            #pragma unroll
            for (int c = 0; c < 32; c++) {
                startc[c] = run; cursors[c] = run; run += hist[c];
            }
        }
        __syncthreads();
        for (int kk = 0; kk < nk; kk++) {
            if (pk[kk] >= 0) {
                int pos = atomicAdd(&cursors[pk[kk] & 31], 1);
                stage[pos] = pk[kk] >> 5;
            }
        }
        __syncthreads();
        myst = startc[i_local];
        mycnt = hist[i_local];
    }
    if (node >= N_NODES) return;    // all syncs already done

    float xr_c[CHANS], att_c[CHANS];
    #pragma unroll
    for (int c = 0; c < CHANS; c++) {
        xr_c[c]  = xr[(size_t)node * HC + h * CHANS + c];
        att_c[c] = att[h * CHANS + c];
    }
    float m = -INFINITY, l = 0.f;
    float acc[CHANS];
    #pragma unroll
    for (int c = 0; c < CHANS; c++) acc[c] = 0.f;

    auto process = [&](int j) {
        const float* xlp = xl + (size_t)j * HC + h * CHANS;
        float v[CHANS];
        float s = 0.f;
        #pragma unroll
        for (int c = 0; c < CHANS; c++) {
            v[c] = xlp[c];
            float t = v[c] + xr_c[c];
            t = (t > 0.f) ? t : NEG_SLOPE * t;
            s += att_c[c] * t;
        }
        float mn = fmaxf(m, s);
        float scale = __expf(m - mn);
        float p = __expf(s - mn);
        l = l * scale + p;
        #pragma unroll
        for (int c = 0; c < CHANS; c++) acc[c] = acc[c] * scale + p * v[c];
        m = mn;
    };

    if (fast) {
        for (int k = 0; k < mycnt; k++) process(stage[myst + k]);
    } else {
        for (int k = 0; k < n; k++) {
            int p = tmp[base + k];
            if ((p & 31) == i_local) process(p >> 5);
        }
    }

    float inv = 1.f / (l + 1e-16f);
    #pragma unroll
    for (int c = 0; c < CHANS; c++) {
        float z = acc[c] * inv + bias[h * CHANS + c];
        y[(size_t)node * HC + h * CHANS + c] = (z > 0.f) ? z : (__expf(z) - 1.f);
    }
}

// ---------------------------------------------------------------------------
extern "C" void kernel_launch(void* const* d_in, const int* in_sizes, int n_in,
                              void* d_out, int out_size, void* d_ws, size_t ws_size,
                              hipStream_t stream) {
    const float* x_in = (const float*)d_in[0];
    const void*  ei   = d_in[1];
    const float* Wl[3] = {(const float*)d_in[2], (const float*)d_in[6],  (const float*)d_in[10]};
    const float* Wr[3] = {(const float*)d_in[3], (const float*)d_in[7],  (const float*)d_in[11]};
    const float* At[3] = {(const float*)d_in[4], (const float*)d_in[8],  (const float*)d_in[12]};
    const float* Bi[3] = {(const float*)d_in[5], (const float*)d_in[9],  (const float*)d_in[13]};
    float* out = (float*)d_out;

    char* ws = (char*)d_ws;
    size_t off = 0;
    auto alloc = [&](size_t bytes) {
        void* p = ws + off;
        off += (bytes + 255) & ~(size_t)255;
        return p;
    };
    float* xl      = (float*)alloc((size_t)N_NODES * HC * sizeof(float));
    float* xr      = (float*)alloc((size_t)N_NODES * HC * sizeof(float));
    float* buf     = (float*)alloc((size_t)N_NODES * HC * sizeof(float));
    int*   tmp     = (int*)alloc((size_t)E_TOT * sizeof(int));
    int*   bcount  = (int*)alloc((size_t)NBUCK * sizeof(int));
    int*   bbase   = (int*)alloc((size_t)(NBUCK + 1) * sizeof(int));
    int*   bcursor = (int*)alloc((size_t)NBUCK * sizeof(int));
    int*   flag    = (int*)alloc(256);

    // --- build bucketed edge list (once per launch) ---
    detect_mode_kernel<<<1, 64, 0, stream>>>(ei, flag);
    hipMemsetAsync(bcount, 0, (size_t)NBUCK * sizeof(int), stream);
    count_bucket_kernel<<<256, 256, 0, stream>>>(ei, flag, bcount);
    scan_buckets_kernel<<<1, 1024, 0, stream>>>(bcount, bbase, bcursor);
    int eblocks = (E_TOT + 255) / 256;
    scatter_bucket_kernel<<<eblocks, 256, 0, stream>>>(ei, flag, bcursor, tmp);

    // --- 3 GATv2 layers ---
    int gemm_blocks = (N_NODES + 63) / 64;
    const float* cur = x_in;
    int din = F_IN;
    for (int layer = 0; layer < 3; layer++) {
        gemm_xlxr_kernel<<<gemm_blocks, 256, 0, stream>>>(cur, Wl[layer], Wr[layer],
                                                          din, xl, xr);
        float* y = (layer == 2) ? out : buf;
        fused_agg_kernel<<<NBUCK, 256, 0, stream>>>(xl, xr, At[layer], Bi[layer],
                                                    bbase, tmp, y);
        cur = buf;
        din = HC;
    }
}

// Round 3
// 512.336 us; speedup vs baseline: 1.5101x; 1.4554x over previous
//
#include <hip/hip_runtime.h>
#include <hip/hip_bf16.h>

#define N_NODES 50000
#define HEADS 8
#define CHANS 10
#define HC 80
#define F_IN 128
#define E_EDGES 1600000
#define E_TOT (E_EDGES + N_NODES)
#define NEG_SLOPE 0.2f
#define NBUCK 1563            // ceil(50000 / 32)
#define CAP 2048              // max edges per bucket fast path (mean 1088, sigma ~33)
#define NCHUNK 256
#define CHUNK ((E_TOT + NCHUNK - 1) / NCHUNK)

// ---------------------------------------------------------------------------
// Detect whether edge_index arrived as int64 (odd int32 words all zero) or int32
__global__ void detect_mode_kernel(const void* ei, int* flag) {
    const int* p = (const int*)ei;
    int tid = threadIdx.x;
    bool ok = (p[2 * tid + 1] == 0) && (p[2 * (tid + 64) + 1] == 0);
    unsigned long long m = __ballot(ok);
    if (tid == 0) *flag = (m == ~0ull) ? 1 : 0;
}

__device__ inline void load_edge(const void* ei, int is64, int e, int& src, int& dst) {
    if (e < E_EDGES) {
        if (is64) {
            src = (int)((const long long*)ei)[e];
            dst = (int)((const long long*)ei)[E_EDGES + e];
        } else {
            src = ((const int*)ei)[e];
            dst = ((const int*)ei)[E_EDGES + e];
        }
    } else {
        src = dst = e - E_EDGES;
    }
}

__device__ inline int load_dst(const void* ei, int is64, int e) {
    if (e < E_EDGES) {
        if (is64) return (int)((const long long*)ei)[E_EDGES + e];
        return ((const int*)ei)[E_EDGES + e];
    }
    return e - E_EDGES;
}

// ---------------------------------------------------------------------------
// Phase 1: per-chunk bucket histogram. No global atomics.
__global__ __launch_bounds__(256) void hist_kernel(
        const void* ei, const int* __restrict__ flag, int* __restrict__ hist) {
    __shared__ int h[NBUCK];
    for (int i = threadIdx.x; i < NBUCK; i += 256) h[i] = 0;
    __syncthreads();
    int blk = blockIdx.x;
    int e0 = blk * CHUNK, e1 = min(e0 + CHUNK, E_TOT);
    int is64 = *flag;
    for (int e = e0 + threadIdx.x; e < e1; e += 4 * 256) {
        int d[4]; int cnt = 0;
        #pragma unroll
        for (int u = 0; u < 4; u++) {
            int ee = e + u * 256;
            if (ee < e1) { d[u] = load_dst(ei, is64, ee); cnt = u + 1; }
        }
        #pragma unroll
        for (int u = 0; u < 4; u++)
            if (u < cnt) atomicAdd(&h[d[u] >> 5], 1);
    }
    __syncthreads();
    for (int i = threadIdx.x; i < NBUCK; i += 256) hist[blk * NBUCK + i] = h[i];
}

// ---------------------------------------------------------------------------
// Per-bucket column exclusive scan over the NCHUNK chunk entries (in place),
// emitting bucket totals. Thread = bucket; loads/stores coalesced across threads.
__global__ __launch_bounds__(256) void colscan_kernel(
        int* __restrict__ hist, int* __restrict__ total) {
    int b = blockIdx.x * 256 + threadIdx.x;
    if (b >= NBUCK) return;
    int run = 0;
    for (int blk = 0; blk < NCHUNK; blk++) {
        int t = hist[blk * NBUCK + b];
        hist[blk * NBUCK + b] = run;
        run += t;
    }
    total[b] = run;
}

// ---------------------------------------------------------------------------
// Single-block exclusive scan over total[NBUCK] -> bbase
__global__ void scan_total_kernel(const int* __restrict__ total, int* __restrict__ bbase) {
    __shared__ int wsum[16];
    __shared__ int wpre[16];
    __shared__ int carry;
    int tid = threadIdx.x;
    int lane = tid & 63, w = tid >> 6;
    if (tid == 0) carry = 0;
    __syncthreads();
    for (int base = 0; base < NBUCK; base += 1024) {
        int idx = base + tid;
        int v = (idx < NBUCK) ? total[idx] : 0;
        int sv = v;
        #pragma unroll
        for (int off = 1; off < 64; off <<= 1) {
            int t = __shfl_up(sv, off, 64);
            if (lane >= off) sv += t;
        }
        if (lane == 63) wsum[w] = sv;
        __syncthreads();
        if (w == 0) {
            int s = (lane < 16) ? wsum[lane] : 0;
            #pragma unroll
            for (int off = 1; off < 16; off <<= 1) {
                int t = __shfl_up(s, off, 64);
                if (lane >= off) s += t;
            }
            if (lane < 16) wpre[lane] = s;
        }
        __syncthreads();
        int pre = carry + ((w > 0) ? wpre[w - 1] : 0);
        if (idx < NBUCK) bbase[idx] = pre + sv - v;
        __syncthreads();
        if (tid == 0) carry += wpre[15];
        __syncthreads();
    }
}

// ---------------------------------------------------------------------------
// Phase 3: deterministic-placement scatter. LDS cursors only; no global atomics.
__global__ __launch_bounds__(256) void scatter_sort_kernel(
        const void* ei, const int* __restrict__ flag,
        const int* __restrict__ hist, const int* __restrict__ bbase,
        int* __restrict__ tmp) {
    __shared__ int cur[NBUCK];
    int blk = blockIdx.x;
    for (int i = threadIdx.x; i < NBUCK; i += 256)
        cur[i] = bbase[i] + hist[blk * NBUCK + i];
    __syncthreads();
    int e0 = blk * CHUNK, e1 = min(e0 + CHUNK, E_TOT);
    int is64 = *flag;
    for (int e = e0 + threadIdx.x; e < e1; e += 4 * 256) {
        int s[4], d[4]; int cnt = 0;
        #pragma unroll
        for (int u = 0; u < 4; u++) {
            int ee = e + u * 256;
            if (ee < e1) { load_edge(ei, is64, ee, s[u], d[u]); cnt = u + 1; }
        }
        #pragma unroll
        for (int u = 0; u < 4; u++) {
            if (u < cnt) {
                int pos = atomicAdd(&cur[d[u] >> 5], 1);
                tmp[pos] = (s[u] << 5) | (d[u] & 31);
            }
        }
    }
}

// ---------------------------------------------------------------------------
// xl = x @ Wl, xr = x @ Wr.  x: [N, din], Wl/Wr: [din, 80].
__global__ __launch_bounds__(256) void gemm_xlxr_kernel(
        const float* __restrict__ x, const float* __restrict__ wl,
        const float* __restrict__ wr, int din,
        float* __restrict__ xl, float* __restrict__ xr) {
    __shared__ float xs[16 * 64];    // [k][node]
    __shared__ float ws[16 * 160];   // [k][col]
    int tid = threadIdx.x;
    int n0 = blockIdx.x * 64;
    int tn = tid >> 4, tc = tid & 15;
    float acc[4][10];
    #pragma unroll
    for (int i = 0; i < 4; i++)
        #pragma unroll
        for (int j = 0; j < 10; j++) acc[i][j] = 0.f;

    int nkt = din >> 4;
    int lr = tid >> 2;
    int lc = (tid & 3) * 4;

    for (int kt = 0; kt < nkt; kt++) {
        float4 xv4 = make_float4(0.f, 0.f, 0.f, 0.f);
        int n = n0 + lr;
        if (n < N_NODES)
            xv4 = *(const float4*)(x + (size_t)n * din + kt * 16 + lc);
        __syncthreads();
        xs[(lc + 0) * 64 + lr] = xv4.x;
        xs[(lc + 1) * 64 + lr] = xv4.y;
        xs[(lc + 2) * 64 + lr] = xv4.z;
        xs[(lc + 3) * 64 + lr] = xv4.w;
        #pragma unroll
        for (int rep = 0; rep < 10; rep++) {
            int flat = rep * 256 + tid;
            int k = flat / 160, c = flat % 160;
            int kg = kt * 16 + k;
            float wv = (c < 80) ? wl[kg * 80 + c] : wr[kg * 80 + (c - 80)];
            ws[k * 160 + c] = wv;
        }
        __syncthreads();
        #pragma unroll
        for (int k = 0; k < 16; k++) {
            float4 xv = *(const float4*)(&xs[k * 64 + tn * 4]);
            float xa[4] = {xv.x, xv.y, xv.z, xv.w};
            #pragma unroll
            for (int j = 0; j < 10; j++) {
                float wv = ws[k * 160 + tc * 10 + j];
                #pragma unroll
                for (int i = 0; i < 4; i++) acc[i][j] += xa[i] * wv;
            }
        }
    }
    float* outp = (tc < 8) ? xl : xr;
    int cbase = (tc < 8) ? tc * 10 : (tc - 8) * 10;
    #pragma unroll
    for (int i = 0; i < 4; i++) {
        int n = n0 + tn * 4 + i;
        if (n < N_NODES) {
            #pragma unroll
            for (int j = 0; j < 10; j++)
                outp[(size_t)n * HC + cbase + j] = acc[i][j];
        }
    }
}

// ---------------------------------------------------------------------------
// Fused per-bucket sort + online-softmax aggregation.
// Block = bucket = 32 nodes x 8 heads = 256 threads.
__global__ __launch_bounds__(256) void fused_agg_kernel(
        const float* __restrict__ xl, const float* __restrict__ xr,
        const float* __restrict__ att, const float* __restrict__ bias,
        const int* __restrict__ bbase, const int* __restrict__ total,
        const int* __restrict__ tmp, float* __restrict__ y) {
    __shared__ int stage[CAP];
    __shared__ int hist[32];
    __shared__ int startc[32];
    __shared__ int cursors[32];
    int tid = threadIdx.x;
    int b = blockIdx.x;
    int base = bbase[b];
    int n = total[b];

    int i_local = tid >> 3, h = tid & 7;
    int node = b * 32 + i_local;

    bool fast = (n <= CAP);
    int myst = 0, mycnt = 0;
    if (fast) {
        if (tid < 32) hist[tid] = 0;
        __syncthreads();
        int pk[CAP / 256];
        int nk = (n + 255) >> 8;
        for (int kk = 0; kk < nk; kk++) {
            int idx = kk * 256 + tid;
            pk[kk] = -1;
            if (idx < n) {
                int p = tmp[base + idx];
                pk[kk] = p;
                atomicAdd(&hist[p & 31], 1);
            }
        }
        __syncthreads();
        if (tid == 0) {
            int run = 0;
            #pragma unroll
            for (int c = 0; c < 32; c++) {
                startc[c] = run; cursors[c] = run; run += hist[c];
            }
        }
        __syncthreads();
        for (int kk = 0; kk < nk; kk++) {
            if (pk[kk] >= 0) {
                int pos = atomicAdd(&cursors[pk[kk] & 31], 1);
                stage[pos] = pk[kk] >> 5;
            }
        }
        __syncthreads();
        myst = startc[i_local];
        mycnt = hist[i_local];
    }
    if (node >= N_NODES) return;    // all syncs already done

    float xr_c[CHANS], att_c[CHANS];
    #pragma unroll
    for (int c = 0; c < CHANS; c++) {
        xr_c[c]  = xr[(size_t)node * HC + h * CHANS + c];
        att_c[c] = att[h * CHANS + c];
    }
    float m = -INFINITY, l = 0.f;
    float acc[CHANS];
    #pragma unroll
    for (int c = 0; c < CHANS; c++) acc[c] = 0.f;

    auto process = [&](int j) {
        const float* xlp = xl + (size_t)j * HC + h * CHANS;
        float v[CHANS];
        float s = 0.f;
        #pragma unroll
        for (int c = 0; c < CHANS; c++) {
            v[c] = xlp[c];
            float t = v[c] + xr_c[c];
            t = (t > 0.f) ? t : NEG_SLOPE * t;
            s += att_c[c] * t;
        }
        float mn = fmaxf(m, s);
        float scale = __expf(m - mn);
        float p = __expf(s - mn);
        l = l * scale + p;
        #pragma unroll
        for (int c = 0; c < CHANS; c++) acc[c] = acc[c] * scale + p * v[c];
        m = mn;
    };

    if (fast) {
        for (int k = 0; k < mycnt; k++) process(stage[myst + k]);
    } else {
        for (int k = 0; k < n; k++) {
            int p = tmp[base + k];
            if ((p & 31) == i_local) process(p >> 5);
        }
    }

    float inv = 1.f / (l + 1e-16f);
    #pragma unroll
    for (int c = 0; c < CHANS; c++) {
        float z = acc[c] * inv + bias[h * CHANS + c];
        y[(size_t)node * HC + h * CHANS + c] = (z > 0.f) ? z : (__expf(z) - 1.f);
    }
}

// ---------------------------------------------------------------------------
extern "C" void kernel_launch(void* const* d_in, const int* in_sizes, int n_in,
                              void* d_out, int out_size, void* d_ws, size_t ws_size,
                              hipStream_t stream) {
    const float* x_in = (const float*)d_in[0];
    const void*  ei   = d_in[1];
    const float* Wl[3] = {(const float*)d_in[2], (const float*)d_in[6],  (const float*)d_in[10]};
    const float* Wr[3] = {(const float*)d_in[3], (const float*)d_in[7],  (const float*)d_in[11]};
    const float* At[3] = {(const float*)d_in[4], (const float*)d_in[8],  (const float*)d_in[12]};
    const float* Bi[3] = {(const float*)d_in[5], (const float*)d_in[9],  (const float*)d_in[13]};
    float* out = (float*)d_out;

    char* ws = (char*)d_ws;
    size_t off = 0;
    auto alloc = [&](size_t bytes) {
        void* p = ws + off;
        off += (bytes + 255) & ~(size_t)255;
        return p;
    };
    float* xl    = (float*)alloc((size_t)N_NODES * HC * sizeof(float));
    float* xr    = (float*)alloc((size_t)N_NODES * HC * sizeof(float));
    float* buf   = (float*)alloc((size_t)N_NODES * HC * sizeof(float));
    int*   tmp   = (int*)alloc((size_t)E_TOT * sizeof(int));
    int*   hist  = (int*)alloc((size_t)NCHUNK * NBUCK * sizeof(int));
    int*   total = (int*)alloc((size_t)NBUCK * sizeof(int));
    int*   bbase = (int*)alloc((size_t)NBUCK * sizeof(int));
    int*   flag  = (int*)alloc(256);

    // --- build bucketed edge list: deterministic counting sort, no global atomics ---
    detect_mode_kernel<<<1, 64, 0, stream>>>(ei, flag);
    hist_kernel<<<NCHUNK, 256, 0, stream>>>(ei, flag, hist);
    colscan_kernel<<<(NBUCK + 255) / 256, 256, 0, stream>>>(hist, total);
    scan_total_kernel<<<1, 1024, 0, stream>>>(total, bbase);
    scatter_sort_kernel<<<NCHUNK, 256, 0, stream>>>(ei, flag, hist, bbase, tmp);

    // --- 3 GATv2 layers ---
    int gemm_blocks = (N_NODES + 63) / 64;
    const float* cur = x_in;
    int din = F_IN;
    for (int layer = 0; layer < 3; layer++) {
        gemm_xlxr_kernel<<<gemm_blocks, 256, 0, stream>>>(cur, Wl[layer], Wr[layer],
                                                          din, xl, xr);
        float* y = (layer == 2) ? out : buf;
        fused_agg_kernel<<<NBUCK, 256, 0, stream>>>(xl, xr, At[layer], Bi[layer],
                                                    bbase, total, tmp, y);
        cur = buf;
        din = HC;
    }
}

// Round 4
// 490.440 us; speedup vs baseline: 1.5776x; 1.0446x over previous
//
#include <hip/hip_runtime.h>
#include <hip/hip_bf16.h>

#define N_NODES 50000
#define HEADS 8
#define CHANS 10
#define HC 80
#define F_IN 128
#define E_EDGES 1600000
#define E_TOT (E_EDGES + N_NODES)
#define NEG_SLOPE 0.2f
#define NBUCK 3125            // 50000 / 16 exactly (16 nodes per bucket)
#define CAP 1024              // max edges per bucket fast path (mean 544, sigma ~23)
#define NCHUNK 256
#define CHUNK ((E_TOT + NCHUNK - 1) / NCHUNK)

// ---------------------------------------------------------------------------
// Detect whether edge_index arrived as int64 (odd int32 words all zero) or int32
__global__ void detect_mode_kernel(const void* ei, int* flag) {
    const int* p = (const int*)ei;
    int tid = threadIdx.x;
    bool ok = (p[2 * tid + 1] == 0) && (p[2 * (tid + 64) + 1] == 0);
    unsigned long long m = __ballot(ok);
    if (tid == 0) *flag = (m == ~0ull) ? 1 : 0;
}

__device__ inline void load_edge(const void* ei, int is64, int e, int& src, int& dst) {
    if (e < E_EDGES) {
        if (is64) {
            src = (int)((const long long*)ei)[e];
            dst = (int)((const long long*)ei)[E_EDGES + e];
        } else {
            src = ((const int*)ei)[e];
            dst = ((const int*)ei)[E_EDGES + e];
        }
    } else {
        src = dst = e - E_EDGES;
    }
}

__device__ inline int load_dst(const void* ei, int is64, int e) {
    if (e < E_EDGES) {
        if (is64) return (int)((const long long*)ei)[E_EDGES + e];
        return ((const int*)ei)[E_EDGES + e];
    }
    return e - E_EDGES;
}

// ---------------------------------------------------------------------------
// Phase 1: per-chunk bucket histogram. No global atomics.
__global__ __launch_bounds__(256) void hist_kernel(
        const void* ei, const int* __restrict__ flag, int* __restrict__ hist) {
    __shared__ int h[NBUCK];
    for (int i = threadIdx.x; i < NBUCK; i += 256) h[i] = 0;
    __syncthreads();
    int blk = blockIdx.x;
    int e0 = blk * CHUNK, e1 = min(e0 + CHUNK, E_TOT);
    int is64 = *flag;
    for (int e = e0 + threadIdx.x; e < e1; e += 4 * 256) {
        int d[4]; int cnt = 0;
        #pragma unroll
        for (int u = 0; u < 4; u++) {
            int ee = e + u * 256;
            if (ee < e1) { d[u] = load_dst(ei, is64, ee); cnt = u + 1; }
        }
        #pragma unroll
        for (int u = 0; u < 4; u++)
            if (u < cnt) atomicAdd(&h[d[u] >> 4], 1);
    }
    __syncthreads();
    for (int i = threadIdx.x; i < NBUCK; i += 256) hist[blk * NBUCK + i] = h[i];
}

// ---------------------------------------------------------------------------
// Per-bucket column exclusive scan over the NCHUNK chunk entries (in place),
// emitting bucket totals. Thread = bucket; loads/stores coalesced across threads.
__global__ __launch_bounds__(256) void colscan_kernel(
        int* __restrict__ hist, int* __restrict__ total) {
    int b = blockIdx.x * 256 + threadIdx.x;
    if (b >= NBUCK) return;
    int run = 0;
    for (int blk = 0; blk < NCHUNK; blk++) {
        int t = hist[blk * NBUCK + b];
        hist[blk * NBUCK + b] = run;
        run += t;
    }
    total[b] = run;
}

// ---------------------------------------------------------------------------
// Single-block exclusive scan over total[NBUCK] -> bbase
__global__ void scan_total_kernel(const int* __restrict__ total, int* __restrict__ bbase) {
    __shared__ int wsum[16];
    __shared__ int wpre[16];
    __shared__ int carry;
    int tid = threadIdx.x;
    int lane = tid & 63, w = tid >> 6;
    if (tid == 0) carry = 0;
    __syncthreads();
    for (int base = 0; base < NBUCK; base += 1024) {
        int idx = base + tid;
        int v = (idx < NBUCK) ? total[idx] : 0;
        int sv = v;
        #pragma unroll
        for (int off = 1; off < 64; off <<= 1) {
            int t = __shfl_up(sv, off, 64);
            if (lane >= off) sv += t;
        }
        if (lane == 63) wsum[w] = sv;
        __syncthreads();
        if (w == 0) {
            int s = (lane < 16) ? wsum[lane] : 0;
            #pragma unroll
            for (int off = 1; off < 16; off <<= 1) {
                int t = __shfl_up(s, off, 64);
                if (lane >= off) s += t;
            }
            if (lane < 16) wpre[lane] = s;
        }
        __syncthreads();
        int pre = carry + ((w > 0) ? wpre[w - 1] : 0);
        if (idx < NBUCK) bbase[idx] = pre + sv - v;
        __syncthreads();
        if (tid == 0) carry += wpre[15];
        __syncthreads();
    }
}

// ---------------------------------------------------------------------------
// Phase 3: deterministic-placement scatter. LDS cursors only; no global atomics.
__global__ __launch_bounds__(256) void scatter_sort_kernel(
        const void* ei, const int* __restrict__ flag,
        const int* __restrict__ hist, const int* __restrict__ bbase,
        int* __restrict__ tmp) {
    __shared__ int cur[NBUCK];
    int blk = blockIdx.x;
    for (int i = threadIdx.x; i < NBUCK; i += 256)
        cur[i] = bbase[i] + hist[blk * NBUCK + i];
    __syncthreads();
    int e0 = blk * CHUNK, e1 = min(e0 + CHUNK, E_TOT);
    int is64 = *flag;
    for (int e = e0 + threadIdx.x; e < e1; e += 4 * 256) {
        int s[4], d[4]; int cnt = 0;
        #pragma unroll
        for (int u = 0; u < 4; u++) {
            int ee = e + u * 256;
            if (ee < e1) { load_edge(ei, is64, ee, s[u], d[u]); cnt = u + 1; }
        }
        #pragma unroll
        for (int u = 0; u < 4; u++) {
            if (u < cnt) {
                int pos = atomicAdd(&cur[d[u] >> 4], 1);
                tmp[pos] = (s[u] << 4) | (d[u] & 15);
            }
        }
    }
}

// ---------------------------------------------------------------------------
// xl = x @ Wl, xr = x @ Wr.  x: [N, din], Wl/Wr: [din, 80].
__global__ __launch_bounds__(256) void gemm_xlxr_kernel(
        const float* __restrict__ x, const float* __restrict__ wl,
        const float* __restrict__ wr, int din,
        float* __restrict__ xl, float* __restrict__ xr) {
    __shared__ float xs[16 * 64];    // [k][node]
    __shared__ float ws[16 * 160];   // [k][col]
    int tid = threadIdx.x;
    int n0 = blockIdx.x * 64;
    int tn = tid >> 4, tc = tid & 15;
    float acc[4][10];
    #pragma unroll
    for (int i = 0; i < 4; i++)
        #pragma unroll
        for (int j = 0; j < 10; j++) acc[i][j] = 0.f;

    int nkt = din >> 4;
    int lr = tid >> 2;
    int lc = (tid & 3) * 4;

    for (int kt = 0; kt < nkt; kt++) {
        float4 xv4 = make_float4(0.f, 0.f, 0.f, 0.f);
        int n = n0 + lr;
        if (n < N_NODES)
            xv4 = *(const float4*)(x + (size_t)n * din + kt * 16 + lc);
        __syncthreads();
        xs[(lc + 0) * 64 + lr] = xv4.x;
        xs[(lc + 1) * 64 + lr] = xv4.y;
        xs[(lc + 2) * 64 + lr] = xv4.z;
        xs[(lc + 3) * 64 + lr] = xv4.w;
        #pragma unroll
        for (int rep = 0; rep < 10; rep++) {
            int flat = rep * 256 + tid;
            int k = flat / 160, c = flat % 160;
            int kg = kt * 16 + k;
            float wv = (c < 80) ? wl[kg * 80 + c] : wr[kg * 80 + (c - 80)];
            ws[k * 160 + c] = wv;
        }
        __syncthreads();
        #pragma unroll
        for (int k = 0; k < 16; k++) {
            float4 xv = *(const float4*)(&xs[k * 64 + tn * 4]);
            float xa[4] = {xv.x, xv.y, xv.z, xv.w};
            #pragma unroll
            for (int j = 0; j < 10; j++) {
                float wv = ws[k * 160 + tc * 10 + j];
                #pragma unroll
                for (int i = 0; i < 4; i++) acc[i][j] += xa[i] * wv;
            }
        }
    }
    float* outp = (tc < 8) ? xl : xr;
    int cbase = (tc < 8) ? tc * 10 : (tc - 8) * 10;
    #pragma unroll
    for (int i = 0; i < 4; i++) {
        int n = n0 + tn * 4 + i;
        if (n < N_NODES) {
            #pragma unroll
            for (int j = 0; j < 10; j++)
                outp[(size_t)n * HC + cbase + j] = acc[i][j];
        }
    }
}

// ---------------------------------------------------------------------------
// Fused per-bucket sort + online-softmax aggregation.
// Block = bucket = 16 nodes x 8 heads x 2 edge-splits = 256 threads.
// Each (node,head) pair is handled by 2 threads (8 lanes apart) processing
// alternating edges; partial online-softmax states merge via shfl_xor(8).
// Inner loop batches 4 edges to keep 4 row-gathers in flight (ILP).
__global__ __launch_bounds__(256) void fused_agg_kernel(
        const float* __restrict__ xl, const float* __restrict__ xr,
        const float* __restrict__ att, const float* __restrict__ bias,
        const int* __restrict__ bbase, const int* __restrict__ total,
        const int* __restrict__ tmp, float* __restrict__ y) {
    __shared__ int stage[CAP];
    __shared__ int hist16[16];
    __shared__ int startc[16];
    __shared__ int cursors[16];
    int tid = threadIdx.x;
    int b = blockIdx.x;
    int base = bbase[b];
    int n = total[b];

    int h = tid & 7;
    int split = (tid >> 3) & 1;
    int i_local = tid >> 4;
    int node = b * 16 + i_local;    // 50000 = 16*3125: always in range

    bool fast = (n <= CAP);
    int myst = 0, mycnt = 0;
    if (fast) {
        if (tid < 16) hist16[tid] = 0;
        __syncthreads();
        int pk[CAP / 256];
        int nk = (n + 255) >> 8;
        for (int kk = 0; kk < nk; kk++) {
            int idx = kk * 256 + tid;
            pk[kk] = -1;
            if (idx < n) {
                int p = tmp[base + idx];
                pk[kk] = p;
                atomicAdd(&hist16[p & 15], 1);
            }
        }
        __syncthreads();
        if (tid == 0) {
            int run = 0;
            #pragma unroll
            for (int c = 0; c < 16; c++) {
                startc[c] = run; cursors[c] = run; run += hist16[c];
            }
        }
        __syncthreads();
        for (int kk = 0; kk < nk; kk++) {
            if (pk[kk] >= 0) {
                int pos = atomicAdd(&cursors[pk[kk] & 15], 1);
                stage[pos] = pk[kk] >> 4;
            }
        }
        __syncthreads();
        myst = startc[i_local];
        mycnt = hist16[i_local];
    }

    float xr_c[CHANS], att_c[CHANS];
    #pragma unroll
    for (int c = 0; c < CHANS; c++) {
        xr_c[c]  = xr[(size_t)node * HC + h * CHANS + c];
        att_c[c] = att[h * CHANS + c];
    }
    float m = -INFINITY, l = 0.f;
    float acc[CHANS];
    #pragma unroll
    for (int c = 0; c < CHANS; c++) acc[c] = 0.f;

    auto score_of = [&](const float* __restrict__ v) {
        float s = 0.f;
        #pragma unroll
        for (int c = 0; c < CHANS; c++) {
            float t = v[c] + xr_c[c];
            t = (t > 0.f) ? t : NEG_SLOPE * t;
            s += att_c[c] * t;
        }
        return s;
    };
    auto merge1 = [&](float s, const float* __restrict__ v) {
        float mn = fmaxf(m, s);
        float scale = __expf(m - mn);
        float p = __expf(s - mn);
        l = l * scale + p;
        #pragma unroll
        for (int c = 0; c < CHANS; c++) acc[c] = acc[c] * scale + p * v[c];
        m = mn;
    };

    if (fast) {
        // this split's entries: myst+split, myst+split+2, ...
        int cnt_s = (mycnt > split) ? ((mycnt - split + 1) >> 1) : 0;
        int k0 = myst + split;
        int kk = 0;
        for (; kk + 4 <= cnt_s; kk += 4) {
            int j0 = stage[k0 + 2 * (kk + 0)];
            int j1 = stage[k0 + 2 * (kk + 1)];
            int j2 = stage[k0 + 2 * (kk + 2)];
            int j3 = stage[k0 + 2 * (kk + 3)];
            const float* p0 = xl + (size_t)j0 * HC + h * CHANS;
            const float* p1 = xl + (size_t)j1 * HC + h * CHANS;
            const float* p2 = xl + (size_t)j2 * HC + h * CHANS;
            const float* p3 = xl + (size_t)j3 * HC + h * CHANS;
            float v0[CHANS], v1[CHANS], v2[CHANS], v3[CHANS];
            #pragma unroll
            for (int c = 0; c < CHANS; c++) { v0[c] = p0[c]; v1[c] = p1[c]; v2[c] = p2[c]; v3[c] = p3[c]; }
            float s0 = score_of(v0), s1 = score_of(v1), s2 = score_of(v2), s3 = score_of(v3);
            float mb = fmaxf(fmaxf(fmaxf(s0, s1), fmaxf(s2, s3)), m);
            float scale = __expf(m - mb);
            float p0e = __expf(s0 - mb), p1e = __expf(s1 - mb);
            float p2e = __expf(s2 - mb), p3e = __expf(s3 - mb);
            l = l * scale + p0e + p1e + p2e + p3e;
            #pragma unroll
            for (int c = 0; c < CHANS; c++)
                acc[c] = acc[c] * scale + p0e * v0[c] + p1e * v1[c] + p2e * v2[c] + p3e * v3[c];
            m = mb;
        }
        for (; kk < cnt_s; kk++) {
            int j = stage[k0 + 2 * kk];
            const float* p = xl + (size_t)j * HC + h * CHANS;
            float v[CHANS];
            #pragma unroll
            for (int c = 0; c < CHANS; c++) v[c] = p[c];
            merge1(score_of(v), v);
        }
    } else {
        // slow path: scan all, filter by node, alternate matches between splits
        int match = 0;
        for (int k = 0; k < n; k++) {
            int p = tmp[base + k];
            if ((p & 15) == i_local) {
                if ((match & 1) == split) {
                    int j = p >> 4;
                    const float* pp = xl + (size_t)j * HC + h * CHANS;
                    float v[CHANS];
                    #pragma unroll
                    for (int c = 0; c < CHANS; c++) v[c] = pp[c];
                    merge1(score_of(v), v);
                }
                match++;
            }
        }
    }

    // merge the two splits' states (partner is 8 lanes away in the same wave)
    float m2 = __shfl_xor(m, 8, 64);
    float l2 = __shfl_xor(l, 8, 64);
    float mn = fmaxf(m, m2);
    float sc1 = __expf(m - mn), sc2 = __expf(m2 - mn);
    float lt = l * sc1 + l2 * sc2;
    float accm[CHANS];
    #pragma unroll
    for (int c = 0; c < CHANS; c++) {
        float a2 = __shfl_xor(acc[c], 8, 64);
        accm[c] = acc[c] * sc1 + a2 * sc2;
    }
    if (split == 0) {
        float inv = 1.f / (lt + 1e-16f);
        #pragma unroll
        for (int c = 0; c < CHANS; c++) {
            float z = accm[c] * inv + bias[h * CHANS + c];
            y[(size_t)node * HC + h * CHANS + c] = (z > 0.f) ? z : (__expf(z) - 1.f);
        }
    }
}

// ---------------------------------------------------------------------------
extern "C" void kernel_launch(void* const* d_in, const int* in_sizes, int n_in,
                              void* d_out, int out_size, void* d_ws, size_t ws_size,
                              hipStream_t stream) {
    const float* x_in = (const float*)d_in[0];
    const void*  ei   = d_in[1];
    const float* Wl[3] = {(const float*)d_in[2], (const float*)d_in[6],  (const float*)d_in[10]};
    const float* Wr[3] = {(const float*)d_in[3], (const float*)d_in[7],  (const float*)d_in[11]};
    const float* At[3] = {(const float*)d_in[4], (const float*)d_in[8],  (const float*)d_in[12]};
    const float* Bi[3] = {(const float*)d_in[5], (const float*)d_in[9],  (const float*)d_in[13]};
    float* out = (float*)d_out;

    char* ws = (char*)d_ws;
    size_t off = 0;
    auto alloc = [&](size_t bytes) {
        void* p = ws + off;
        off += (bytes + 255) & ~(size_t)255;
        return p;
    };
    float* xl    = (float*)alloc((size_t)N_NODES * HC * sizeof(float));
    float* xr    = (float*)alloc((size_t)N_NODES * HC * sizeof(float));
    float* buf   = (float*)alloc((size_t)N_NODES * HC * sizeof(float));
    int*   tmp   = (int*)alloc((size_t)E_TOT * sizeof(int));
    int*   hist  = (int*)alloc((size_t)NCHUNK * NBUCK * sizeof(int));
    int*   total = (int*)alloc((size_t)NBUCK * sizeof(int));
    int*   bbase = (int*)alloc((size_t)NBUCK * sizeof(int));
    int*   flag  = (int*)alloc(256);

    // --- build bucketed edge list: deterministic counting sort, no global atomics ---
    detect_mode_kernel<<<1, 64, 0, stream>>>(ei, flag);
    hist_kernel<<<NCHUNK, 256, 0, stream>>>(ei, flag, hist);
    colscan_kernel<<<(NBUCK + 255) / 256, 256, 0, stream>>>(hist, total);
    scan_total_kernel<<<1, 1024, 0, stream>>>(total, bbase);
    scatter_sort_kernel<<<NCHUNK, 256, 0, stream>>>(ei, flag, hist, bbase, tmp);

    // --- 3 GATv2 layers ---
    int gemm_blocks = (N_NODES + 63) / 64;
    const float* cur = x_in;
    int din = F_IN;
    for (int layer = 0; layer < 3; layer++) {
        gemm_xlxr_kernel<<<gemm_blocks, 256, 0, stream>>>(cur, Wl[layer], Wr[layer],
                                                          din, xl, xr);
        float* y = (layer == 2) ? out : buf;
        fused_agg_kernel<<<NBUCK, 256, 0, stream>>>(xl, xr, At[layer], Bi[layer],
                                                    bbase, total, tmp, y);
        cur = buf;
        din = HC;
    }
}